// Round 1
// baseline (2251.463 us; speedup 1.0000x reference)
//
#include <hip/hip_runtime.h>

// Problem constants (B, C, W, H = 2, 64, 96, 96)
constexpr int BATCH = 2;
constexpr int CH    = 64;
constexpr int NPOS  = 96 * 96;      // 9216
constexpr int SPLIT = 8;            // j-range splits per i-tile
constexpr int JT    = NPOS / SPLIT; // 1152 j's per block

// ---------------------------------------------------------------------------
// Kernel 1: QKV projection.
// x: (B, 64, N) row-major.  Outputs position-major: Q,K: (B*N, 8), V: (B*N, 64)
// ---------------------------------------------------------------------------
__global__ __launch_bounds__(256) void qkv_kernel(
    const float* __restrict__ x,
    const float* __restrict__ wq, const float* __restrict__ bq,
    const float* __restrict__ wk, const float* __restrict__ bk,
    const float* __restrict__ wv, const float* __restrict__ bv,
    float* __restrict__ Q, float* __restrict__ K, float* __restrict__ V)
{
    __shared__ float W[80][64];   // rows 0-7: wq, 8-15: wk, 16-79: wv
    __shared__ float bias[80];
    const int tid = threadIdx.x;
    for (int idx = tid; idx < 80 * 64; idx += 256) {
        int o = idx >> 6, c = idx & 63;
        float w;
        if (o < 8)       w = wq[o * 64 + c];
        else if (o < 16) w = wk[(o - 8) * 64 + c];
        else             w = wv[(o - 16) * 64 + c];
        W[o][c] = w;
    }
    if (tid < 80) {
        float bb;
        if (tid < 8)       bb = bq[tid];
        else if (tid < 16) bb = bk[tid - 8];
        else               bb = bv[tid - 16];
        bias[tid] = bb;
    }
    __syncthreads();

    const int pos = blockIdx.x * 256 + tid;      // 0 .. B*N-1
    const int b = pos / NPOS;
    const int i = pos - b * NPOS;

    float xr[64];
    #pragma unroll
    for (int c = 0; c < 64; ++c)
        xr[c] = x[(size_t)(b * CH + c) * NPOS + i];   // coalesced across lanes

    for (int o = 0; o < 80; ++o) {
        float s = bias[o];
        #pragma unroll
        for (int c4 = 0; c4 < 16; ++c4) {
            float4 w4 = *(const float4*)&W[o][c4 * 4];   // wave-uniform -> broadcast
            s += w4.x * xr[c4*4+0] + w4.y * xr[c4*4+1]
               + w4.z * xr[c4*4+2] + w4.w * xr[c4*4+3];
        }
        if (o < 8)       Q[(size_t)pos * 8  + o]        = s;
        else if (o < 16) K[(size_t)pos * 8  + (o - 8)]  = s;
        else             V[(size_t)pos * 64 + (o - 16)] = s;
    }
}

// ---------------------------------------------------------------------------
// Kernel 2a: softmax-row denominators  L[j] = sum_m exp(q_j . k_m)
// Block: 128 j's (2 per lane), m-range JT per block (SPLIT-way split).
// ---------------------------------------------------------------------------
__global__ __launch_bounds__(256) void denom_kernel(
    const float* __restrict__ Q, const float* __restrict__ K,
    float* __restrict__ L)
{
    __shared__ float kt[64][8];
    const int tid  = threadIdx.x;
    const int wv   = tid >> 6;
    const int lane = tid & 63;
    const int b    = blockIdx.y;
    const int jt   = blockIdx.x / SPLIT;        // i-tile index 0..71
    const int ms   = blockIdx.x - jt * SPLIT;   // m-split 0..7
    const int j0   = jt * 128;
    const int m0   = ms * JT;
    const size_t base = (size_t)b * NPOS;

    float4 qa0 = *(const float4*)&Q[(base + j0 + lane) * 8];
    float4 qa1 = *(const float4*)&Q[(base + j0 + lane) * 8 + 4];
    float4 qb0 = *(const float4*)&Q[(base + j0 + 64 + lane) * 8];
    float4 qb1 = *(const float4*)&Q[(base + j0 + 64 + lane) * 8 + 4];
    float l0 = 0.f, l1 = 0.f;

    for (int t = 0; t < JT / 64; ++t) {        // 18 staged tiles of 64 m's
        __syncthreads();
        for (int idx = tid; idx < 128; idx += 256) {
            int m = idx >> 1, f = idx & 1;
            *((float4*)&kt[m][f * 4]) =
                *(const float4*)&K[(base + m0 + t * 64 + m) * 8 + f * 4];
        }
        __syncthreads();
        #pragma unroll
        for (int jj = 0; jj < 16; ++jj) {
            int m = wv * 16 + jj;              // wave-uniform -> LDS broadcast
            float4 k0 = *(const float4*)&kt[m][0];
            float4 k1 = *(const float4*)&kt[m][4];
            float s0 = qa0.x*k0.x + qa0.y*k0.y + qa0.z*k0.z + qa0.w*k0.w
                     + qa1.x*k1.x + qa1.y*k1.y + qa1.z*k1.z + qa1.w*k1.w;
            float s1 = qb0.x*k0.x + qb0.y*k0.y + qb0.z*k0.z + qb0.w*k0.w
                     + qb1.x*k1.x + qb1.y*k1.y + qb1.z*k1.z + qb1.w*k1.w;
            l0 += __expf(s0);
            l1 += __expf(s1);
        }
    }
    __hip_atomic_fetch_add(&L[base + j0 + lane],      l0,
                           __ATOMIC_RELAXED, __HIP_MEMORY_SCOPE_AGENT);
    __hip_atomic_fetch_add(&L[base + j0 + 64 + lane], l1,
                           __ATOMIC_RELAXED, __HIP_MEMORY_SCOPE_AGENT);
}

// ---------------------------------------------------------------------------
// Kernel 2b: main pass.  out[c,i] += sum_j exp(k_i . q_j) * (v[c,j]/L[j])
// Block: 128 i's (2 per lane), j-range JT (SPLIT-way split). j-tiles of 64
// staged in LDS rows [q_j(8) | v'_j(64)]; wave-uniform j -> broadcast reads.
// ---------------------------------------------------------------------------
__global__ __launch_bounds__(256) void attn_kernel(
    const float* __restrict__ Qm, const float* __restrict__ Km,
    const float* __restrict__ Vm, const float* __restrict__ L,
    float* __restrict__ ACC)
{
    __shared__ float jv[64][72];   // 18.4 KB
    const int tid  = threadIdx.x;
    const int wv   = tid >> 6;
    const int lane = tid & 63;
    const int b    = blockIdx.y;
    const int it   = blockIdx.x / SPLIT;
    const int js   = blockIdx.x - it * SPLIT;
    const int i0   = it * 128;
    const int j0   = js * JT;
    const size_t base = (size_t)b * NPOS;

    float4 ka0 = *(const float4*)&Km[(base + i0 + lane) * 8];
    float4 ka1 = *(const float4*)&Km[(base + i0 + lane) * 8 + 4];
    float4 kb0 = *(const float4*)&Km[(base + i0 + 64 + lane) * 8];
    float4 kb1 = *(const float4*)&Km[(base + i0 + 64 + lane) * 8 + 4];

    float acc0[64], acc1[64];
    #pragma unroll
    for (int c = 0; c < 64; ++c) { acc0[c] = 0.f; acc1[c] = 0.f; }

    for (int t = 0; t < JT / 64; ++t) {
        __syncthreads();
        // stage 64 rows of [q_j | v_j / L_j]
        for (int idx = tid; idx < 64 * 18; idx += 256) {
            int j = idx / 18, f = idx - j * 18;
            int jg = j0 + t * 64 + j;
            float4 val;
            if (f < 2) {
                val = *(const float4*)&Qm[(base + jg) * 8 + f * 4];
            } else {
                val = *(const float4*)&Vm[(base + jg) * 64 + (f - 2) * 4];
                float r = 1.0f / L[base + jg];
                val.x *= r; val.y *= r; val.z *= r; val.w *= r;
            }
            *((float4*)&jv[j][f * 4]) = val;
        }
        __syncthreads();

        #pragma unroll 4
        for (int jj = 0; jj < 16; ++jj) {
            int j = wv * 16 + jj;              // wave-uniform j
            const float* row = &jv[j][0];
            float4 q0 = *(const float4*)(row);
            float4 q1 = *(const float4*)(row + 4);
            float s0 = ka0.x*q0.x + ka0.y*q0.y + ka0.z*q0.z + ka0.w*q0.w
                     + ka1.x*q1.x + ka1.y*q1.y + ka1.z*q1.z + ka1.w*q1.w;
            float s1 = kb0.x*q0.x + kb0.y*q0.y + kb0.z*q0.z + kb0.w*q0.w
                     + kb1.x*q1.x + kb1.y*q1.y + kb1.z*q1.z + kb1.w*q1.w;
            float p0 = __expf(s0);
            float p1 = __expf(s1);
            #pragma unroll
            for (int c4 = 0; c4 < 16; ++c4) {
                float4 v4 = *(const float4*)(row + 8 + c4 * 4);
                acc0[c4*4+0] += p0 * v4.x; acc0[c4*4+1] += p0 * v4.y;
                acc0[c4*4+2] += p0 * v4.z; acc0[c4*4+3] += p0 * v4.w;
                acc1[c4*4+0] += p1 * v4.x; acc1[c4*4+1] += p1 * v4.y;
                acc1[c4*4+2] += p1 * v4.z; acc1[c4*4+3] += p1 * v4.w;
            }
        }
    }

    float* a0 = &ACC[(base + i0 + lane) * 64];
    float* a1 = &ACC[(base + i0 + 64 + lane) * 64];
    #pragma unroll
    for (int c = 0; c < 64; ++c) {
        __hip_atomic_fetch_add(a0 + c, acc0[c],
                               __ATOMIC_RELAXED, __HIP_MEMORY_SCOPE_AGENT);
        __hip_atomic_fetch_add(a1 + c, acc1[c],
                               __ATOMIC_RELAXED, __HIP_MEMORY_SCOPE_AGENT);
    }
}

// ---------------------------------------------------------------------------
// Kernel 3: out[b,c,i] = gamma * ACC[b,i,c] + x[b,c,i]
// ---------------------------------------------------------------------------
__global__ __launch_bounds__(256) void finalize_kernel(
    const float* __restrict__ ACC, const float* __restrict__ x,
    const float* __restrict__ gamma, float* __restrict__ out)
{
    const int pos = blockIdx.x * 256 + threadIdx.x;
    const int b = pos / NPOS;
    const int i = pos - b * NPOS;
    const float g = gamma[0];
    const float* a = &ACC[(size_t)pos * 64];
    const size_t xbase = (size_t)b * CH * NPOS + i;
    #pragma unroll
    for (int c = 0; c < 64; ++c) {
        out[xbase + (size_t)c * NPOS] = g * a[c] + x[xbase + (size_t)c * NPOS];
    }
}

// ---------------------------------------------------------------------------
extern "C" void kernel_launch(void* const* d_in, const int* in_sizes, int n_in,
                              void* d_out, int out_size, void* d_ws, size_t ws_size,
                              hipStream_t stream)
{
    const float* x     = (const float*)d_in[0];
    const float* wq    = (const float*)d_in[1];
    const float* bq    = (const float*)d_in[2];
    const float* wk    = (const float*)d_in[3];
    const float* bk    = (const float*)d_in[4];
    const float* wv    = (const float*)d_in[5];
    const float* bv    = (const float*)d_in[6];
    const float* gamma = (const float*)d_in[7];
    float* out = (float*)d_out;

    float* ws = (float*)d_ws;
    float* Q   = ws;                                 // B*N*8
    float* K   = Q + (size_t)BATCH * NPOS * 8;       // B*N*8
    float* V   = K + (size_t)BATCH * NPOS * 8;       // B*N*64
    float* L   = V + (size_t)BATCH * NPOS * 64;      // B*N
    float* ACC = L + (size_t)BATCH * NPOS;           // B*N*64

    // zero the accumulated buffers (L and ACC are contiguous)
    hipMemsetAsync(L, 0,
                   (size_t)(BATCH * NPOS + BATCH * NPOS * 64) * sizeof(float),
                   stream);

    qkv_kernel<<<dim3(BATCH * NPOS / 256), 256, 0, stream>>>(
        x, wq, bq, wk, bk, wv, bv, Q, K, V);

    denom_kernel<<<dim3((NPOS / 128) * SPLIT, BATCH), 256, 0, stream>>>(Q, K, L);

    attn_kernel<<<dim3((NPOS / 128) * SPLIT, BATCH), 256, 0, stream>>>(
        Q, K, V, L, ACC);

    finalize_kernel<<<dim3(BATCH * NPOS / 256), 256, 0, stream>>>(
        ACC, x, gamma, out);
}

// Round 2
// 291.548 us; speedup vs baseline: 7.7224x; 7.7224x over previous
//
#include <hip/hip_runtime.h>

using half4   = __attribute__((ext_vector_type(4))) _Float16;
using floatx4 = __attribute__((ext_vector_type(4))) float;

constexpr int BATCH = 2;
constexpr int CH    = 64;
constexpr int NPOS  = 96 * 96;        // 9216
constexpr int NT    = NPOS / 16;      // 576 sixteen-wide tiles

// ---------------------------------------------------------------------------
// K1: QKV projection. Writes V (fp32, pos-major) and Q/K fragments (f16,
// d padded 8->16 with zeros) in exact MFMA lane order:
//   Qf[b][jt][lane][r] = Q[j = jt*16 + (lane&15)][d = 4*(lane>>4)+r]
// ---------------------------------------------------------------------------
__global__ __launch_bounds__(256) void qkv_kernel(
    const float* __restrict__ x,
    const float* __restrict__ wq, const float* __restrict__ bq,
    const float* __restrict__ wk, const float* __restrict__ bk,
    const float* __restrict__ wv, const float* __restrict__ bv,
    _Float16* __restrict__ Qf, _Float16* __restrict__ Kf,
    float* __restrict__ V)
{
    __shared__ float W[80][64];
    __shared__ float bias[80];
    const int tid = threadIdx.x;
    for (int idx = tid; idx < 80 * 64; idx += 256) {
        int o = idx >> 6, c = idx & 63;
        float w;
        if (o < 8)       w = wq[o * 64 + c];
        else if (o < 16) w = wk[(o - 8) * 64 + c];
        else             w = wv[(o - 16) * 64 + c];
        W[o][c] = w;
    }
    if (tid < 80) {
        float bb;
        if (tid < 8)       bb = bq[tid];
        else if (tid < 16) bb = bk[tid - 8];
        else               bb = bv[tid - 16];
        bias[tid] = bb;
    }
    __syncthreads();

    const int pos = blockIdx.x * 256 + tid;     // blocks never straddle batch
    const int b = pos / NPOS;
    const int i = pos - b * NPOS;

    float xr[64];
    #pragma unroll
    for (int c = 0; c < 64; ++c)
        xr[c] = x[(size_t)(b * CH + c) * NPOS + i];   // coalesced

    float qk[16];
    for (int o = 0; o < 80; ++o) {
        float s = bias[o];
        #pragma unroll
        for (int c4 = 0; c4 < 16; ++c4) {
            float4 w4 = *(const float4*)&W[o][c4 * 4];   // wave-uniform
            s += w4.x * xr[c4*4+0] + w4.y * xr[c4*4+1]
               + w4.z * xr[c4*4+2] + w4.w * xr[c4*4+3];
        }
        if (o < 16) qk[o] = s;
        else        V[(size_t)pos * 64 + (o - 16)] = s;
    }

    const int jt = i >> 4, jl = i & 15;
    const size_t fbase = (size_t)(b * NT + jt) * 64;
    #pragma unroll
    for (int g = 0; g < 4; ++g) {
        half4 qh, kh;
        #pragma unroll
        for (int r = 0; r < 4; ++r) {
            qh[r] = (g < 2) ? (_Float16)qk[4*g + r]     : (_Float16)0.f;
            kh[r] = (g < 2) ? (_Float16)qk[8 + 4*g + r] : (_Float16)0.f;
        }
        *(half4*)&Qf[(fbase + jl + 16*g) * 4] = qh;
        *(half4*)&Kf[(fbase + jl + 16*g) * 4] = kh;
    }
}

// ---------------------------------------------------------------------------
// K2: denominators. One wave per 16-j tile; E-MFMA over all i tiles,
// per-lane partial sums, 16-lane butterfly reduce, writes rL = 1/L. No atomics.
// ---------------------------------------------------------------------------
__global__ __launch_bounds__(256) void denom_kernel(
    const _Float16* __restrict__ Qf, const _Float16* __restrict__ Kf,
    float* __restrict__ rL)
{
    const int w = threadIdx.x >> 6, l = threadIdx.x & 63;
    const int b = blockIdx.y;
    const int jt = blockIdx.x * 4 + w;
    const half4 qf = *(const half4*)&Qf[((size_t)(b * NT + jt) * 64 + l) * 4];
    const half4* __restrict__ kfb = (const half4*)(Kf + (size_t)b * NT * 256);
    float s0 = 0.f, s1 = 0.f, s2 = 0.f, s3 = 0.f;
    #pragma unroll 4
    for (int it = 0; it < NT; ++it) {
        half4 kf = kfb[it * 64 + l];
        floatx4 z = {0.f, 0.f, 0.f, 0.f};
        floatx4 e = __builtin_amdgcn_mfma_f32_16x16x16f16(qf, kf, z, 0, 0, 0);
        s0 += __expf(e[0]); s1 += __expf(e[1]);
        s2 += __expf(e[2]); s3 += __expf(e[3]);
    }
    #pragma unroll
    for (int m = 1; m < 16; m <<= 1) {
        s0 += __shfl_xor(s0, m, 64);
        s1 += __shfl_xor(s1, m, 64);
        s2 += __shfl_xor(s2, m, 64);
        s3 += __shfl_xor(s3, m, 64);
    }
    if ((l & 15) == 0) {
        const int g = l >> 4;
        float* p = &rL[(size_t)b * NPOS + jt * 16 + 4 * g];
        p[0] = 1.f / s0; p[1] = 1.f / s1; p[2] = 1.f / s2; p[3] = 1.f / s3;
    }
}

// ---------------------------------------------------------------------------
// K3: V' fragments (f16) in A-operand lane order:
//   Vf[b][jt][t][lane][r] = V[j = jt*16+4*(lane>>4)+r][c = 16t+(lane&15)] * rL[j]
// ---------------------------------------------------------------------------
__global__ __launch_bounds__(256) void prepv_kernel(
    const float* __restrict__ V, const float* __restrict__ rL,
    _Float16* __restrict__ Vf)
{
    const int tid = blockIdx.x * 256 + threadIdx.x;   // 0 .. 2*576*4*64-1
    const int b   = tid / (NT * 256);
    const int rem = tid - b * (NT * 256);
    const int jt  = rem >> 8;
    const int t   = (rem >> 6) & 3;
    const int l   = rem & 63;
    const int g = l >> 4, cl = l & 15;
    half4 o;
    #pragma unroll
    for (int r = 0; r < 4; ++r) {
        int j = jt * 16 + 4 * g + r;
        float v = V[((size_t)b * NPOS + j) * 64 + 16 * t + cl]
                * rL[(size_t)b * NPOS + j];
        o[r] = (_Float16)v;
    }
    *(half4*)&Vf[(size_t)tid * 4] = o;
}

// ---------------------------------------------------------------------------
// K4: flash attention. Block = 32 i's: 4 waves = 2 i-subtiles x 2 j-halves.
// Per 16-j step per wave: 1 E-MFMA -> exp (P stays in regs, C-layout == B-layout
// for 16x16x16) -> 4 PV-MFMAs. Epilogue: combine j-halves via LDS, write
// gamma*acc + x directly to out. No atomics, no LDS in hot loop.
// ---------------------------------------------------------------------------
__global__ __launch_bounds__(256) void attn_kernel(
    const _Float16* __restrict__ Qf, const _Float16* __restrict__ Kf,
    const _Float16* __restrict__ Vf,
    const float* __restrict__ x, const float* __restrict__ gamma,
    float* __restrict__ out)
{
    __shared__ float red[4][64][17];   // +1 pad: conflict-free epilogue
    const int w = threadIdx.x >> 6, l = threadIdx.x & 63;
    const int b    = blockIdx.y;
    const int isub = w >> 1, jpar = w & 1;
    const int it   = blockIdx.x * 2 + isub;
    const int i0   = it * 16;

    const half4 kf = *(const half4*)&Kf[((size_t)(b * NT + it) * 64 + l) * 4];
    const half4* __restrict__ qfb = (const half4*)(Qf + (size_t)b * NT * 256);
    const half4* __restrict__ vfb = (const half4*)(Vf + (size_t)b * NT * 1024);

    floatx4 acc0 = {0.f,0.f,0.f,0.f}, acc1 = {0.f,0.f,0.f,0.f};
    floatx4 acc2 = {0.f,0.f,0.f,0.f}, acc3 = {0.f,0.f,0.f,0.f};

    #pragma unroll 4
    for (int jt = jpar; jt < NT; jt += 2) {
        half4 qf  = qfb[jt * 64 + l];
        half4 vf0 = vfb[(jt * 4 + 0) * 64 + l];
        half4 vf1 = vfb[(jt * 4 + 1) * 64 + l];
        half4 vf2 = vfb[(jt * 4 + 2) * 64 + l];
        half4 vf3 = vfb[(jt * 4 + 3) * 64 + l];
        floatx4 z = {0.f, 0.f, 0.f, 0.f};
        floatx4 e = __builtin_amdgcn_mfma_f32_16x16x16f16(qf, kf, z, 0, 0, 0);
        half4 p;
        p[0] = (_Float16)__expf(e[0]);
        p[1] = (_Float16)__expf(e[1]);
        p[2] = (_Float16)__expf(e[2]);
        p[3] = (_Float16)__expf(e[3]);
        acc0 = __builtin_amdgcn_mfma_f32_16x16x16f16(vf0, p, acc0, 0, 0, 0);
        acc1 = __builtin_amdgcn_mfma_f32_16x16x16f16(vf1, p, acc1, 0, 0, 0);
        acc2 = __builtin_amdgcn_mfma_f32_16x16x16f16(vf2, p, acc2, 0, 0, 0);
        acc3 = __builtin_amdgcn_mfma_f32_16x16x16f16(vf3, p, acc3, 0, 0, 0);
    }

    // park partial sums
    #pragma unroll
    for (int r = 0; r < 4; ++r) {
        red[w][l][r]      = acc0[r];
        red[w][l][4 + r]  = acc1[r];
        red[w][l][8 + r]  = acc2[r];
        red[w][l][12 + r] = acc3[r];
    }
    __syncthreads();

    if (jpar == 0) {
        const float g = gamma[0];
        const int ig = i0 + (l & 15);
        const int cg = 4 * (l >> 4);
        #pragma unroll
        for (int t = 0; t < 4; ++t) {
            floatx4 a = (t == 0) ? acc0 : (t == 1) ? acc1 : (t == 2) ? acc2 : acc3;
            #pragma unroll
            for (int r = 0; r < 4; ++r) {
                float s = a[r] + red[w + 1][l][t * 4 + r];
                int c = 16 * t + cg + r;
                size_t o = ((size_t)(b * CH + c)) * NPOS + ig;
                out[o] = g * s + x[o];
            }
        }
    }
}

// ---------------------------------------------------------------------------
extern "C" void kernel_launch(void* const* d_in, const int* in_sizes, int n_in,
                              void* d_out, int out_size, void* d_ws, size_t ws_size,
                              hipStream_t stream)
{
    const float* x     = (const float*)d_in[0];
    const float* wq    = (const float*)d_in[1];
    const float* bq    = (const float*)d_in[2];
    const float* wk    = (const float*)d_in[3];
    const float* bk    = (const float*)d_in[4];
    const float* wv    = (const float*)d_in[5];
    const float* bv    = (const float*)d_in[6];
    const float* gamma = (const float*)d_in[7];
    float* out = (float*)d_out;

    char* wsb = (char*)d_ws;
    float*    V  = (float*)wsb;                              // 4,718,592 B
    float*    rL = (float*)(wsb + 4718592);                  //    73,728 B
    _Float16* Qf = (_Float16*)(wsb + 4718592 + 73728);       //   589,824 B
    _Float16* Kf = Qf + (size_t)BATCH * NT * 256;            //   589,824 B
    _Float16* Vf = Kf + (size_t)BATCH * NT * 256;            // 2,359,296 B

    qkv_kernel<<<dim3(BATCH * NPOS / 256), 256, 0, stream>>>(
        x, wq, bq, wk, bk, wv, bv, Qf, Kf, V);

    denom_kernel<<<dim3(NT / 4, BATCH), 256, 0, stream>>>(Qf, Kf, rL);

    prepv_kernel<<<dim3(BATCH * NT * 256 / 256), 256, 0, stream>>>(V, rL, Vf);

    attn_kernel<<<dim3(NPOS / 32, BATCH), 256, 0, stream>>>(
        Qf, Kf, Vf, x, gamma, out);
}

// Round 4
// 170.428 us; speedup vs baseline: 13.2106x; 1.7107x over previous
//
#include <hip/hip_runtime.h>

using half2v  = __attribute__((ext_vector_type(2))) _Float16;
using fp16x2  = __attribute__((ext_vector_type(2))) __fp16;
using half4   = __attribute__((ext_vector_type(4))) _Float16;
using floatx4 = __attribute__((ext_vector_type(4))) float;

constexpr int BATCH = 2;
constexpr int NPOS  = 96 * 96;      // 9216
constexpr int NT    = NPOS / 16;    // 576 j/i tiles of 16
constexpr int NTH   = NT / 2;       // 288 tiles per half

#if defined(__has_builtin)
#if __has_builtin(__builtin_amdgcn_exp2f)
#define EXP2(x) __builtin_amdgcn_exp2f(x)
#endif
#endif
#ifndef EXP2
#define EXP2(x) exp2f(x)
#endif

__device__ inline half4 p4_of(floatx4 e) {
    half2v lo = __builtin_bit_cast(half2v,
        __builtin_amdgcn_cvt_pkrtz(EXP2(e[0]), EXP2(e[1])));
    half2v hi = __builtin_bit_cast(half2v,
        __builtin_amdgcn_cvt_pkrtz(EXP2(e[2]), EXP2(e[3])));
    half4 p; p[0] = lo[0]; p[1] = lo[1]; p[2] = hi[0]; p[3] = hi[1];
    return p;
}

// ---------------------------------------------------------------------------
// K1: QKV projection, 4 threads per position (288 blocks). Qf pre-scaled by
// log2(e) so downstream uses raw v_exp_f32. Fragment lane order as R2.
// ---------------------------------------------------------------------------
__global__ __launch_bounds__(256) void qkv_kernel(
    const float* __restrict__ x,
    const float* __restrict__ wq, const float* __restrict__ bq,
    const float* __restrict__ wk, const float* __restrict__ bk,
    const float* __restrict__ wv, const float* __restrict__ bv,
    _Float16* __restrict__ Qf, _Float16* __restrict__ Kf,
    float* __restrict__ V)
{
    __shared__ float W[80][64];
    __shared__ float bias[80];
    const int tid = threadIdx.x;
    for (int idx = tid; idx < 80 * 64; idx += 256) {
        int o = idx >> 6, c = idx & 63;
        float w;
        if (o < 8)       w = wq[o * 64 + c];
        else if (o < 16) w = wk[(o - 8) * 64 + c];
        else             w = wv[(o - 16) * 64 + c];
        W[o][c] = w;
    }
    if (tid < 80) {
        float bb;
        if (tid < 8)       bb = bq[tid];
        else if (tid < 16) bb = bk[tid - 8];
        else               bb = bv[tid - 16];
        bias[tid] = bb;
    }
    __syncthreads();

    const int part = tid >> 6;                    // wave-uniform
    const int pos  = blockIdx.x * 64 + (tid & 63);
    const int b = pos / NPOS;
    const int i = pos - b * NPOS;

    float xr[64];
    #pragma unroll
    for (int c = 0; c < 64; ++c)
        xr[c] = x[(size_t)(b * 64 + c) * NPOS + i];

    #define DOT(O, S) { S = bias[O]; \
        _Pragma("unroll") \
        for (int c4 = 0; c4 < 16; ++c4) { \
            float4 w4 = *(const float4*)&W[O][c4 * 4]; \
            S += w4.x * xr[c4*4+0] + w4.y * xr[c4*4+1] \
               + w4.z * xr[c4*4+2] + w4.w * xr[c4*4+3]; } }

    if (part == 0) {
        float qk[16];
        #pragma unroll
        for (int o = 0; o < 16; ++o) DOT(o, qk[o]);
        #pragma unroll
        for (int o = 16; o < 20; ++o) { float s; DOT(o, s); V[(size_t)pos * 64 + (o - 16)] = s; }
        const int jt = i >> 4, jl = i & 15;
        const size_t fb = (size_t)(b * NT + jt) * 64;
        constexpr float LOG2E = 1.44269504088896f;
        #pragma unroll
        for (int g = 0; g < 4; ++g) {
            half4 qh, kh;
            #pragma unroll
            for (int r = 0; r < 4; ++r) {
                qh[r] = (g < 2) ? (_Float16)(qk[4*g + r] * LOG2E) : (_Float16)0.f;
                kh[r] = (g < 2) ? (_Float16)qk[8 + 4*g + r]       : (_Float16)0.f;
            }
            *(half4*)&Qf[(fb + jl + 16*g) * 4] = qh;
            *(half4*)&Kf[(fb + jl + 16*g) * 4] = kh;
        }
    } else {
        #pragma unroll
        for (int oo = 0; oo < 20; ++oo) {
            int o = part * 20 + oo;
            float s; DOT(o, s);
            V[(size_t)pos * 64 + (o - 16)] = s;
        }
    }
    #undef DOT
}

// ---------------------------------------------------------------------------
// K2: denominators. Block = 64 j's (4 tiles) x i-half; wave = i-eighth with
// all 4 q-tiles persistent (kf load reused 4x). Deterministic 2-half partials.
// ---------------------------------------------------------------------------
__global__ __launch_bounds__(256, 2) void denom_kernel(
    const _Float16* __restrict__ Qf, const _Float16* __restrict__ Kf,
    float* __restrict__ Lp)
{
    __shared__ float LpS[4][64];
    const int tid = threadIdx.x;
    const int w = tid >> 6, l = tid & 63;
    const int jgl = blockIdx.x;         // 0..143
    const int b   = blockIdx.y;
    const int ih  = blockIdx.z;
    const int jt0 = jgl * 4;
    const half4* __restrict__ qfb = (const half4*)Qf + (size_t)b * NT * 64;
    const half4* __restrict__ kfb = (const half4*)Kf + (size_t)b * NT * 64;

    half4 q0 = qfb[(jt0 + 0) * 64 + l];
    half4 q1 = qfb[(jt0 + 1) * 64 + l];
    half4 q2 = qfb[(jt0 + 2) * 64 + l];
    half4 q3 = qfb[(jt0 + 3) * 64 + l];

    float sum[4][4];
    #pragma unroll
    for (int s = 0; s < 4; ++s)
        #pragma unroll
        for (int r = 0; r < 4; ++r) sum[s][r] = 0.f;

    #define DSTEP(KF) do { \
        floatx4 z = {0.f,0.f,0.f,0.f}; \
        floatx4 e0 = __builtin_amdgcn_mfma_f32_16x16x16f16(q0, KF, z, 0,0,0); \
        floatx4 e1 = __builtin_amdgcn_mfma_f32_16x16x16f16(q1, KF, z, 0,0,0); \
        floatx4 e2 = __builtin_amdgcn_mfma_f32_16x16x16f16(q2, KF, z, 0,0,0); \
        floatx4 e3 = __builtin_amdgcn_mfma_f32_16x16x16f16(q3, KF, z, 0,0,0); \
        _Pragma("unroll") \
        for (int r = 0; r < 4; ++r) { \
            sum[0][r] += EXP2(e0[r]); sum[1][r] += EXP2(e1[r]); \
            sum[2][r] += EXP2(e2[r]); sum[3][r] += EXP2(e3[r]); } \
    } while (0)

    const half4* kp = kfb + (size_t)(ih * NTH + w) * 64 + l;
    half4 kf = *kp;
    for (int k = 0; k < 71; ++k) {
        kp += 256;
        half4 kn = *kp;
        DSTEP(kf);
        kf = kn;
    }
    DSTEP(kf);
    #undef DSTEP

    #pragma unroll
    for (int s = 0; s < 4; ++s)
        #pragma unroll
        for (int r = 0; r < 4; ++r)
            #pragma unroll
            for (int m = 1; m < 16; m <<= 1)
                sum[s][r] += __shfl_xor(sum[s][r], m, 64);

    if ((l & 15) == 0) {
        const int g = l >> 4;
        #pragma unroll
        for (int s = 0; s < 4; ++s)
            #pragma unroll
            for (int r = 0; r < 4; ++r)
                LpS[w][s * 16 + 4 * g + r] = sum[s][r];
    }
    __syncthreads();
    if (tid < 64) {
        float tot = LpS[0][tid] + LpS[1][tid] + LpS[2][tid] + LpS[3][tid];
        Lp[((size_t)ih * BATCH + b) * NPOS + jgl * 64 + tid] = tot;
    }
}

// ---------------------------------------------------------------------------
// K3: V' fragments: Vf[...] = V[j][c] / (Lp0[j]+Lp1[j]), A-operand lane order.
// ---------------------------------------------------------------------------
__global__ __launch_bounds__(256) void prepv_kernel(
    const float* __restrict__ V, const float* __restrict__ Lp,
    _Float16* __restrict__ Vf)
{
    const int tid = blockIdx.x * 256 + threadIdx.x;
    const int b   = tid / (NT * 256);
    const int rem = tid - b * (NT * 256);
    const int jt  = rem >> 8;
    const int t4  = (rem >> 6) & 3;
    const int l   = rem & 63;
    const int g = l >> 4, cl = l & 15;
    half4 o;
    #pragma unroll
    for (int r = 0; r < 4; ++r) {
        int j = jt * 16 + 4 * g + r;
        float Lv = Lp[(size_t)b * NPOS + j] + Lp[(size_t)(BATCH + b) * NPOS + j];
        float v = V[((size_t)b * NPOS + j) * 64 + 16 * t4 + cl] / Lv;
        o[r] = (_Float16)v;
    }
    *(half4*)&Vf[(size_t)tid * 4] = o;
}

// ---------------------------------------------------------------------------
// K4: attention. Block = 64 i's x j-half; wave = j-eighth holding all 4
// i-subtiles (kf persistent, 16 floatx4 accums) -> each qf/vf load feeds
// 4 E-MFMAs + 16 PV-MFMAs (4x L2-traffic cut). Depth-1 register prefetch.
// In-block 4-way combine via LDS, partial tile -> ACC[half].
// ---------------------------------------------------------------------------
__global__ __launch_bounds__(256, 2) void attn_kernel(
    const _Float16* __restrict__ Qf, const _Float16* __restrict__ Kf,
    const _Float16* __restrict__ Vf, float* __restrict__ ACC)
{
    __shared__ float red[4][4][64][17];
    const int tid = threadIdx.x;
    const int w = tid >> 6, l = tid & 63;
    const int igl = blockIdx.x;        // 0..143
    const int b   = blockIdx.y;
    const int h   = blockIdx.z;
    const int it0 = igl * 4, i0 = igl * 64;
    const half4* __restrict__ qfb = (const half4*)Qf + (size_t)b * NT * 64;
    const half4* __restrict__ kfb = (const half4*)Kf + (size_t)b * NT * 64;
    const half4* __restrict__ vfb = (const half4*)Vf + (size_t)b * NT * 256;

    half4 kf0 = kfb[(it0 + 0) * 64 + l];
    half4 kf1 = kfb[(it0 + 1) * 64 + l];
    half4 kf2 = kfb[(it0 + 2) * 64 + l];
    half4 kf3 = kfb[(it0 + 3) * 64 + l];

    floatx4 acc[4][4];
    #pragma unroll
    for (int s = 0; s < 4; ++s)
        #pragma unroll
        for (int t = 0; t < 4; ++t)
            acc[s][t] = (floatx4){0.f, 0.f, 0.f, 0.f};

    #define ASTEP(QF, V0, V1, V2, V3) do { \
        floatx4 z = {0.f,0.f,0.f,0.f}; \
        floatx4 e0 = __builtin_amdgcn_mfma_f32_16x16x16f16(QF, kf0, z, 0,0,0); \
        floatx4 e1 = __builtin_amdgcn_mfma_f32_16x16x16f16(QF, kf1, z, 0,0,0); \
        floatx4 e2 = __builtin_amdgcn_mfma_f32_16x16x16f16(QF, kf2, z, 0,0,0); \
        floatx4 e3 = __builtin_amdgcn_mfma_f32_16x16x16f16(QF, kf3, z, 0,0,0); \
        half4 p0 = p4_of(e0), p1 = p4_of(e1), p2 = p4_of(e2), p3 = p4_of(e3); \
        acc[0][0] = __builtin_amdgcn_mfma_f32_16x16x16f16(V0, p0, acc[0][0], 0,0,0); \
        acc[0][1] = __builtin_amdgcn_mfma_f32_16x16x16f16(V1, p0, acc[0][1], 0,0,0); \
        acc[0][2] = __builtin_amdgcn_mfma_f32_16x16x16f16(V2, p0, acc[0][2], 0,0,0); \
        acc[0][3] = __builtin_amdgcn_mfma_f32_16x16x16f16(V3, p0, acc[0][3], 0,0,0); \
        acc[1][0] = __builtin_amdgcn_mfma_f32_16x16x16f16(V0, p1, acc[1][0], 0,0,0); \
        acc[1][1] = __builtin_amdgcn_mfma_f32_16x16x16f16(V1, p1, acc[1][1], 0,0,0); \
        acc[1][2] = __builtin_amdgcn_mfma_f32_16x16x16f16(V2, p1, acc[1][2], 0,0,0); \
        acc[1][3] = __builtin_amdgcn_mfma_f32_16x16x16f16(V3, p1, acc[1][3], 0,0,0); \
        acc[2][0] = __builtin_amdgcn_mfma_f32_16x16x16f16(V0, p2, acc[2][0], 0,0,0); \
        acc[2][1] = __builtin_amdgcn_mfma_f32_16x16x16f16(V1, p2, acc[2][1], 0,0,0); \
        acc[2][2] = __builtin_amdgcn_mfma_f32_16x16x16f16(V2, p2, acc[2][2], 0,0,0); \
        acc[2][3] = __builtin_amdgcn_mfma_f32_16x16x16f16(V3, p2, acc[2][3], 0,0,0); \
        acc[3][0] = __builtin_amdgcn_mfma_f32_16x16x16f16(V0, p3, acc[3][0], 0,0,0); \
        acc[3][1] = __builtin_amdgcn_mfma_f32_16x16x16f16(V1, p3, acc[3][1], 0,0,0); \
        acc[3][2] = __builtin_amdgcn_mfma_f32_16x16x16f16(V2, p3, acc[3][2], 0,0,0); \
        acc[3][3] = __builtin_amdgcn_mfma_f32_16x16x16f16(V3, p3, acc[3][3], 0,0,0); \
    } while (0)

    const half4* qp = qfb + (size_t)(h * NTH + w) * 64 + l;
    const half4* vp = vfb + (size_t)(h * NTH + w) * 256 + l;
    half4 qf = *qp;
    half4 v0 = vp[0], v1 = vp[64], v2 = vp[128], v3 = vp[192];
    for (int k = 0; k < 71; ++k) {
        qp += 256; vp += 1024;
        half4 qn  = *qp;
        half4 v0n = vp[0], v1n = vp[64], v2n = vp[128], v3n = vp[192];
        ASTEP(qf, v0, v1, v2, v3);
        qf = qn; v0 = v0n; v1 = v1n; v2 = v2n; v3 = v3n;
    }
    ASTEP(qf, v0, v1, v2, v3);
    #undef ASTEP

    // in-block combine of the 4 j-shards
    #pragma unroll
    for (int s = 0; s < 4; ++s)
        #pragma unroll
        for (int t = 0; t < 4; ++t)
            #pragma unroll
            for (int r = 0; r < 4; ++r)
                red[w][s][l][t * 4 + r] = acc[s][t][r];
    __syncthreads();

    const int s = w;   // wave w owns subtile w
    const int iq = i0 + 16 * s + (l & 15);
    #pragma unroll
    for (int t = 0; t < 4; ++t)
        #pragma unroll
        for (int r = 0; r < 4; ++r) {
            float v = red[0][s][l][t*4+r] + red[1][s][l][t*4+r]
                    + red[2][s][l][t*4+r] + red[3][s][l][t*4+r];
            int c = 16 * t + 4 * (l >> 4) + r;
            ACC[(((size_t)h * BATCH + b) * 64 + c) * NPOS + iq] = v;
        }
}

// ---------------------------------------------------------------------------
// K5: out = gamma * (ACC[0] + ACC[1]) + x   (streaming float4)
// ---------------------------------------------------------------------------
__global__ __launch_bounds__(256) void finalize_kernel(
    const float* __restrict__ ACC, const float* __restrict__ x,
    const float* __restrict__ gamma, float* __restrict__ out)
{
    const size_t idx = (size_t)blockIdx.x * 256 + threadIdx.x;
    constexpr size_t HALF4 = (size_t)BATCH * 64 * NPOS / 4;   // 294912
    const float g = gamma[0];
    float4 a0 = ((const float4*)ACC)[idx];
    float4 a1 = ((const float4*)ACC)[HALF4 + idx];
    float4 xv = ((const float4*)x)[idx];
    float4 o;
    o.x = g * (a0.x + a1.x) + xv.x;
    o.y = g * (a0.y + a1.y) + xv.y;
    o.z = g * (a0.z + a1.z) + xv.z;
    o.w = g * (a0.w + a1.w) + xv.w;
    ((float4*)out)[idx] = o;
}

// ---------------------------------------------------------------------------
extern "C" void kernel_launch(void* const* d_in, const int* in_sizes, int n_in,
                              void* d_out, int out_size, void* d_ws, size_t ws_size,
                              hipStream_t stream)
{
    const float* x     = (const float*)d_in[0];
    const float* wq    = (const float*)d_in[1];
    const float* bq    = (const float*)d_in[2];
    const float* wk    = (const float*)d_in[3];
    const float* bk    = (const float*)d_in[4];
    const float* wv    = (const float*)d_in[5];
    const float* bv    = (const float*)d_in[6];
    const float* gamma = (const float*)d_in[7];
    float* out = (float*)d_out;

    char* wsb = (char*)d_ws;
    float*    V   = (float*)wsb;                         // 4,718,592 B
    float*    Lp  = (float*)(wsb + 4718592);             //   147,456 B
    _Float16* Qf  = (_Float16*)(wsb + 4866048);          //   589,824 B
    _Float16* Kf  = (_Float16*)(wsb + 5455872);          //   589,824 B
    _Float16* Vf  = (_Float16*)(wsb + 6045696);          // 2,359,296 B
    float*    ACC = (float*)(wsb + 8404992);             // 9,437,184 B

    qkv_kernel<<<dim3(BATCH * NPOS / 64), 256, 0, stream>>>(
        x, wq, bq, wk, bk, wv, bv, Qf, Kf, V);

    denom_kernel<<<dim3(NT / 4, BATCH, 2), 256, 0, stream>>>(Qf, Kf, Lp);

    prepv_kernel<<<dim3(BATCH * NT, 1, 1), 256, 0, stream>>>(V, Lp, Vf);

    attn_kernel<<<dim3(NT / 4, BATCH, 2), 256, 0, stream>>>(Qf, Kf, Vf, ACC);

    finalize_kernel<<<dim3(BATCH * 64 * NPOS / 1024), 256, 0, stream>>>(
        ACC, x, gamma, out);
}